// Round 7
// baseline (291.974 us; speedup 1.0000x reference)
//
#include <hip/hip_runtime.h>
#include <hip/hip_bf16.h>

using short8 = __attribute__((ext_vector_type(8))) short;
using f32x4  = __attribute__((ext_vector_type(4))) float;

static constexpr int NN = 50000;   // nodes
static constexpr int NE = 800000;  // edges
static constexpr int MPAD = 50048; // 782 * 64 padded rows for bf16 activations
static constexpr int NB2 = 256;    // dst buckets
static constexpr int BNODE = 196;  // nodes per bucket (256*196 = 50176 >= NN)
static constexpr int CAPB = 4096;  // bucket capacity (mean 3125, sigma ~56)
static constexpr int NCHB = 200;   // pass-A chunks
static constexpr int CHB = NE / NCHB;  // 4000 edges per chunk (exact)

__device__ __forceinline__ float clip100(float v) { return fminf(fmaxf(v, -100.f), 100.f); }
__device__ __forceinline__ unsigned short f2b(float v) {
    __hip_bfloat16 h = __float2bfloat16(v);
    return *reinterpret_cast<unsigned short*>(&h);
}
__device__ __forceinline__ float blo(unsigned int u) { return __uint_as_float(u << 16); }
__device__ __forceinline__ float bhi(unsigned int u) { return __uint_as_float(u & 0xFFFF0000u); }
__device__ __forceinline__ float b2f(unsigned short u) {
    return __uint_as_float(((unsigned int)u) << 16);
}

// ---- per-node aggregation (R2/R6-proven): returns packed 2xbf16 for (d,lane)
// d must be wave-uniform (readfirstlane'd by caller) so rowptr/esrc/dinv loads
// are scalar and the gather base is SGPR + lane*4.
template <bool RES, bool ESCALE>
__device__ __forceinline__ unsigned int aggr_node(const int d, const int lane,
                                                  const unsigned int* __restrict__ As2,
                                                  const int* __restrict__ rowptr,
                                                  const int* __restrict__ esrc,
                                                  const float* __restrict__ dinv,
                                                  const float* __restrict__ bias,
                                                  const float* __restrict__ x) {
    const float dd = dinv[d];
    const unsigned int u = As2[(long)d * 64 + lane];  // self term
    float2 acc;
    if (ESCALE) {
        acc.x = blo(u) * dd;
        acc.y = bhi(u) * dd;
    } else {
        acc.x = blo(u);
        acc.y = bhi(u);
    }
    const int beg = rowptr[d];
    const int end = rowptr[d + 1];
    int i = beg;
    for (; i + 16 <= end; i += 16) {
        int s[16];
#pragma unroll
        for (int e = 0; e < 16; ++e) s[e] = esrc[i + e];
        unsigned int v[16];
#pragma unroll
        for (int e = 0; e < 16; ++e) v[e] = As2[(long)s[e] * 64 + lane];
        float px = 0.f, py = 0.f;
        if (ESCALE) {
#pragma unroll
            for (int e = 0; e < 16; ++e) {
                const float w = dinv[s[e]];
                px = fmaf(blo(v[e]), w, px);
                py = fmaf(bhi(v[e]), w, py);
            }
        } else {
#pragma unroll
            for (int e = 0; e < 16; ++e) {
                px += blo(v[e]);
                py += bhi(v[e]);
            }
        }
        acc.x += px;
        acc.y += py;
    }
    if (i + 8 <= end) {
        const int s0 = esrc[i + 0], s1 = esrc[i + 1], s2 = esrc[i + 2], s3 = esrc[i + 3];
        const int s4 = esrc[i + 4], s5 = esrc[i + 5], s6 = esrc[i + 6], s7 = esrc[i + 7];
        const unsigned int v0 = As2[(long)s0 * 64 + lane];
        const unsigned int v1 = As2[(long)s1 * 64 + lane];
        const unsigned int v2 = As2[(long)s2 * 64 + lane];
        const unsigned int v3 = As2[(long)s3 * 64 + lane];
        const unsigned int v4 = As2[(long)s4 * 64 + lane];
        const unsigned int v5 = As2[(long)s5 * 64 + lane];
        const unsigned int v6 = As2[(long)s6 * 64 + lane];
        const unsigned int v7 = As2[(long)s7 * 64 + lane];
        if (ESCALE) {
            const float w0 = dinv[s0], w1 = dinv[s1], w2 = dinv[s2], w3 = dinv[s3];
            const float w4 = dinv[s4], w5 = dinv[s5], w6 = dinv[s6], w7 = dinv[s7];
            acc.x += ((blo(v0) * w0 + blo(v1) * w1) + (blo(v2) * w2 + blo(v3) * w3)) +
                     ((blo(v4) * w4 + blo(v5) * w5) + (blo(v6) * w6 + blo(v7) * w7));
            acc.y += ((bhi(v0) * w0 + bhi(v1) * w1) + (bhi(v2) * w2 + bhi(v3) * w3)) +
                     ((bhi(v4) * w4 + bhi(v5) * w5) + (bhi(v6) * w6 + bhi(v7) * w7));
        } else {
            acc.x += ((blo(v0) + blo(v1)) + (blo(v2) + blo(v3))) +
                     ((blo(v4) + blo(v5)) + (blo(v6) + blo(v7)));
            acc.y += ((bhi(v0) + bhi(v1)) + (bhi(v2) + bhi(v3))) +
                     ((bhi(v4) + bhi(v5)) + (bhi(v6) + bhi(v7)));
        }
        i += 8;
    }
    if (i + 4 <= end) {
        const int s0 = esrc[i + 0], s1 = esrc[i + 1], s2 = esrc[i + 2], s3 = esrc[i + 3];
        const unsigned int v0 = As2[(long)s0 * 64 + lane];
        const unsigned int v1 = As2[(long)s1 * 64 + lane];
        const unsigned int v2 = As2[(long)s2 * 64 + lane];
        const unsigned int v3 = As2[(long)s3 * 64 + lane];
        if (ESCALE) {
            const float w0 = dinv[s0], w1 = dinv[s1], w2 = dinv[s2], w3 = dinv[s3];
            acc.x += (blo(v0) * w0 + blo(v1) * w1) + (blo(v2) * w2 + blo(v3) * w3);
            acc.y += (bhi(v0) * w0 + bhi(v1) * w1) + (bhi(v2) * w2 + bhi(v3) * w3);
        } else {
            acc.x += (blo(v0) + blo(v1)) + (blo(v2) + blo(v3));
            acc.y += (bhi(v0) + bhi(v1)) + (bhi(v2) + bhi(v3));
        }
        i += 4;
    }
    for (; i < end; ++i) {
        const int s = esrc[i];
        const unsigned int v = As2[(long)s * 64 + lane];
        if (ESCALE) {
            const float w = dinv[s];
            acc.x = fmaf(blo(v), w, acc.x);
            acc.y = fmaf(bhi(v), w, acc.y);
        } else {
            acc.x += blo(v);
            acc.y += bhi(v);
        }
    }
    const float2 bv = ((const float2*)bias)[lane];
    acc.x = fmaxf(fmaf(acc.x, dd, bv.x), 0.f);
    acc.y = fmaxf(fmaf(acc.y, dd, bv.y), 0.f);
    if (RES) {
        const float2 xv = ((const float2*)x)[(long)d * 64 + lane];
        acc.x += clip100(xv.x);
        acc.y += clip100(xv.y);
    }
    return (unsigned int)f2b(acc.x) | ((unsigned int)f2b(acc.y) << 16);
}

// ---------------- K1: bucket (blocks 0..199) || weight cvt (blocks 200..455) -
__global__ __launch_bounds__(256) void k_front(const int* __restrict__ idx,
                                               int2* __restrict__ epair,
                                               int* __restrict__ gcur,
                                               const float* __restrict__ W1,
                                               const float* __restrict__ W2,
                                               const float* __restrict__ Wg,
                                               unsigned short* __restrict__ Wt1,
                                               unsigned short* __restrict__ Wt2,
                                               unsigned short* __restrict__ Wgt) {
    __shared__ int ls[CHB], ld[CHB];
    __shared__ int bcnt[NB2], bb[NB2], bofs[NB2];
    const int tid = threadIdx.x;
    if (blockIdx.x < NCHB) {
        const int beg = blockIdx.x * CHB;
        for (int i = tid; i < CHB; i += 256) {
            ls[i] = idx[beg + i];
            ld[i] = idx[NE + beg + i];
        }
        bcnt[tid] = 0;
        __syncthreads();
        for (int i = tid; i < CHB; i += 256) atomicAdd(&bcnt[ld[i] / BNODE], 1);
        __syncthreads();
        bb[tid] = atomicAdd(&gcur[tid], bcnt[tid]);
        bofs[tid] = 0;
        __syncthreads();
        for (int i = tid; i < CHB; i += 256) {
            const int d = ld[i];
            const int p = d / BNODE;
            const int pos = atomicAdd(&bofs[p], 1);
            epair[p * CAPB + bb[p] + pos] = make_int2(ls[i], d);
        }
    } else {
        const int i = (blockIdx.x - NCHB) * 256 + tid;  // 0..65535
        if (i < 16384) {
            const int n = i >> 7, k = i & 127;
            Wt1[i] = f2b(W1[k * 128 + n]);
        } else if (i < 32768) {
            const int j = i - 16384;
            const int n = j >> 7, k = j & 127;
            Wt2[j] = f2b(W2[k * 128 + n]);
        } else {
            const int j = i - 32768;
            const int n = j >> 8, k = j & 255;
            Wgt[j] = f2b(Wg[k * 128 + n]);
        }
    }
}

// ---------------- K2: sortfill (blocks 0..255) || layer-1 GEMM (256..1037) ---
__global__ __launch_bounds__(256) void k_mid(const int2* __restrict__ epair,
                                             const int* __restrict__ gcur,
                                             int* __restrict__ rowptr,
                                             float* __restrict__ dinv,
                                             int* __restrict__ esrc,
                                             const float* __restrict__ x,
                                             const unsigned short* __restrict__ Wt,
                                             unsigned short* __restrict__ Cb) {
    __shared__ alignas(16) char smem[CAPB * 2 * 4 + 3 * 256 * 4];  // 35840 B union
    const int tid = threadIdx.x;
    if (blockIdx.x < NB2) {
        int* ls   = (int*)smem;
        int* ld   = ls + CAPB;
        int* cntL = ld + CAPB;
        int* sc   = cntL + 256;
        int* cur  = sc + 256;
        const int t = tid;
        const int b = blockIdx.x;
        sc[t] = gcur[t];
        __syncthreads();
        for (int off = 1; off < 256; off <<= 1) {
            const int add = (t >= off) ? sc[t - off] : 0;
            __syncthreads();
            sc[t] += add;
            __syncthreads();
        }
        const int ne = gcur[b];
        const int base = sc[b] - ne;  // exclusive prefix for bucket b
        const int nb0 = b * BNODE;
        const int nn = min(NN - nb0, BNODE);
        if (b == 0 && t == 0) rowptr[NN] = NE;

        for (int i = t; i < ne; i += 256) {
            const int2 p = epair[b * CAPB + i];
            ls[i] = p.x;
            ld[i] = p.y - nb0;  // node-local index in [0, nn)
        }
        cntL[t] = 0;
        __syncthreads();
        for (int i = t; i < ne; i += 256) atomicAdd(&cntL[ld[i]], 1);
        __syncthreads();
        sc[t] = cntL[t];
        __syncthreads();
        for (int off = 1; off < 256; off <<= 1) {
            const int add = (t >= off) ? sc[t - off] : 0;
            __syncthreads();
            sc[t] += add;
            __syncthreads();
        }
        const int excl = sc[t] - cntL[t];
        cur[t] = excl;
        if (t < nn) {
            rowptr[nb0 + t] = base + excl;
            dinv[nb0 + t] = rsqrtf(1.f + (float)cntL[t]);
        }
        __syncthreads();
        for (int i = t; i < ne; i += 256) {
            const int pos = base + atomicAdd(&cur[ld[i]], 1);
            esrc[pos] = ls[i];   // direct scatter, 12.5 KB window (L2)
        }
    } else {
        unsigned short* wl = (unsigned short*)smem;  // 128 x 136 = 34816 B
#pragma unroll
        for (int j = tid; j < 2048; j += 256) {  // 2048 = 128 rows x 16 short8
            const int row = j >> 4, c8 = j & 15;
            *(short8*)(wl + row * 136 + c8 * 8) = *(const short8*)(Wt + row * 128 + c8 * 8);
        }
        __syncthreads();

        const int wv = tid >> 6;
        const int ln = tid & 63;
        const int l16 = ln & 15;
        const int qd = ln >> 4;
        const int rowb = (blockIdx.x - NB2) * 64 + wv * 16;
        const long arow = rowb + l16;
        const int kq = qd * 8;

        f32x4 acc[8];
#pragma unroll
        for (int i = 0; i < 8; ++i) acc[i] = (f32x4){0.f, 0.f, 0.f, 0.f};

#pragma unroll
        for (int kc = 0; kc < 4; ++kc) {
            short8 a = (short8){0, 0, 0, 0, 0, 0, 0, 0};
            if (arow < NN) {
                const float* fp = x + arow * 128 + kc * 32 + kq;
                const float4 f0 = *(const float4*)fp;
                const float4 f1 = *(const float4*)(fp + 4);
                a[0] = (short)f2b(clip100(f0.x));
                a[1] = (short)f2b(clip100(f0.y));
                a[2] = (short)f2b(clip100(f0.z));
                a[3] = (short)f2b(clip100(f0.w));
                a[4] = (short)f2b(clip100(f1.x));
                a[5] = (short)f2b(clip100(f1.y));
                a[6] = (short)f2b(clip100(f1.z));
                a[7] = (short)f2b(clip100(f1.w));
            }
#pragma unroll
            for (int nt = 0; nt < 8; ++nt) {
                const short8 b = *(const short8*)(wl + (nt * 16 + l16) * 136 + kc * 32 + kq);
                acc[nt] = __builtin_amdgcn_mfma_f32_16x16x32_bf16(a, b, acc[nt], 0, 0, 0);
            }
        }

        const int r0 = rowb + qd * 4;
#pragma unroll
        for (int r = 0; r < 4; ++r) {
            const int row = r0 + r;
            if (row < NN) {
#pragma unroll
                for (int nt = 0; nt < 8; ++nt) {
                    Cb[(long)row * 128 + nt * 16 + l16] = f2b(acc[nt][r]);
                }
            }
        }
    }
}

// ---------------- K3: fused layer-1 aggregate + layer-2 GEMM -----------------
// Block owns 64 nodes. 4 waves aggregate 16 nodes each (gather from As, per-
// edge dinv[s] scaling) into a padded LDS tile, then the same block runs the
// K=128 MFMA tile (h1 @ W2 * dinv_row) -> hb. Kills the h1 global round-trip;
// per-block GEMM starts as soon as its own 64 nodes are done.
__global__ __launch_bounds__(256) void k_ag1(const unsigned int* __restrict__ As2,
                                             const unsigned short* __restrict__ Wt2,
                                             unsigned short* __restrict__ Cb,
                                             const int* __restrict__ rowptr,
                                             const int* __restrict__ esrc,
                                             const float* __restrict__ dinv,
                                             const float* __restrict__ b1) {
    __shared__ alignas(16) unsigned int ht[64 * 68];   // 64 rows x 136 shorts (+8 pad)
    __shared__ unsigned short wl[128 * 136];
    const int tid = threadIdx.x;
#pragma unroll
    for (int j = tid; j < 2048; j += 256) {
        const int row = j >> 4, c8 = j & 15;
        *(short8*)(wl + row * 136 + c8 * 8) = *(const short8*)(Wt2 + row * 128 + c8 * 8);
    }
    const int wv = tid >> 6;
    const int ln = tid & 63;
    const int nbase = blockIdx.x * 64 + wv * 16;
#pragma unroll 1
    for (int j = 0; j < 16; ++j) {
        const int d = __builtin_amdgcn_readfirstlane(nbase + j);
        unsigned int pack = 0;
        if (d < NN)
            pack = aggr_node<false, true>(d, ln, As2, rowptr, esrc, dinv, b1, nullptr);
        ht[(wv * 16 + j) * 68 + ln] = pack;
    }
    __syncthreads();

    const int l16 = ln & 15;
    const int qd = ln >> 4;
    const int kq = qd * 8;
    f32x4 acc[8];
#pragma unroll
    for (int i = 0; i < 8; ++i) acc[i] = (f32x4){0.f, 0.f, 0.f, 0.f};
#pragma unroll
    for (int kc = 0; kc < 4; ++kc) {
        const short8 a =
            *(const short8*)((const unsigned short*)ht + (wv * 16 + l16) * 136 + kc * 32 + kq);
#pragma unroll
        for (int nt = 0; nt < 8; ++nt) {
            const short8 b = *(const short8*)(wl + (nt * 16 + l16) * 136 + kc * 32 + kq);
            acc[nt] = __builtin_amdgcn_mfma_f32_16x16x32_bf16(a, b, acc[nt], 0, 0, 0);
        }
    }
    const int r0 = blockIdx.x * 64 + wv * 16 + qd * 4;
#pragma unroll
    for (int r = 0; r < 4; ++r) {
        const int row = r0 + r;
        if (row < NN) {
            const float dv = dinv[row];
#pragma unroll
            for (int nt = 0; nt < 8; ++nt) {
                Cb[(long)row * 128 + nt * 16 + l16] = f2b(acc[nt][r] * dv);
            }
        }
    }
}

// ---------------- K4: fused layer-2 aggregate + gate GEMM + output -----------
// Same block structure. Aggregates h (with residual) into LDS, then the gate
// GEMM (K=256, split into two K=128 phases; x re-read is L2-hot from the
// residual), sigmoid, out = h * g. Kills the hb round-trip AND the separate
// gate kernel.
__global__ __launch_bounds__(256) void k_ag2(const unsigned int* __restrict__ Hs2,
                                             const float* __restrict__ x,
                                             const unsigned short* __restrict__ Wgt,
                                             const int* __restrict__ rowptr,
                                             const int* __restrict__ esrc,
                                             const float* __restrict__ dinv,
                                             const float* __restrict__ b2,
                                             const float* __restrict__ bg,
                                             float* __restrict__ out) {
    __shared__ alignas(16) unsigned int ht[64 * 68];
    __shared__ unsigned short wl[128 * 136];
    const int tid = threadIdx.x;
    // stage gate weights, K-half 1 (cols 0..127: the h part)
#pragma unroll
    for (int j = tid; j < 2048; j += 256) {
        const int row = j >> 4, c8 = j & 15;
        *(short8*)(wl + row * 136 + c8 * 8) = *(const short8*)(Wgt + row * 256 + c8 * 8);
    }
    const int wv = tid >> 6;
    const int ln = tid & 63;
    const int nbase = blockIdx.x * 64 + wv * 16;
#pragma unroll 1
    for (int j = 0; j < 16; ++j) {
        const int d = __builtin_amdgcn_readfirstlane(nbase + j);
        unsigned int pack = 0;
        if (d < NN)
            pack = aggr_node<true, false>(d, ln, Hs2, rowptr, esrc, dinv, b2, x);
        ht[(wv * 16 + j) * 68 + ln] = pack;
    }
    __syncthreads();

    const int l16 = ln & 15;
    const int qd = ln >> 4;
    const int kq = qd * 8;
    f32x4 acc[8];
#pragma unroll
    for (int i = 0; i < 8; ++i) acc[i] = (f32x4){0.f, 0.f, 0.f, 0.f};

    // phase 1: K = 0..127 (h from LDS)
#pragma unroll
    for (int kc = 0; kc < 4; ++kc) {
        const short8 a =
            *(const short8*)((const unsigned short*)ht + (wv * 16 + l16) * 136 + kc * 32 + kq);
#pragma unroll
        for (int nt = 0; nt < 8; ++nt) {
            const short8 b = *(const short8*)(wl + (nt * 16 + l16) * 136 + kc * 32 + kq);
            acc[nt] = __builtin_amdgcn_mfma_f32_16x16x32_bf16(a, b, acc[nt], 0, 0, 0);
        }
    }
    __syncthreads();  // phase-1 wl reads complete before overwrite

    // stage gate weights, K-half 2 (cols 128..255: the x part)
#pragma unroll
    for (int j = tid; j < 2048; j += 256) {
        const int row = j >> 4, c8 = j & 15;
        *(short8*)(wl + row * 136 + c8 * 8) = *(const short8*)(Wgt + row * 256 + 128 + c8 * 8);
    }
    __syncthreads();

    // phase 2: K = 128..255 (clip(x), L2-hot from the residual read)
    {
        const long arow = (long)blockIdx.x * 64 + wv * 16 + l16;
        const bool valid = arow < NN;
        const float* fp = x + arow * 128 + kq;
#pragma unroll
        for (int kc = 0; kc < 4; ++kc) {
            short8 a = (short8){0, 0, 0, 0, 0, 0, 0, 0};
            if (valid) {
                const float4 f0 = *(const float4*)(fp + kc * 32);
                const float4 f1 = *(const float4*)(fp + kc * 32 + 4);
                a[0] = (short)f2b(clip100(f0.x));
                a[1] = (short)f2b(clip100(f0.y));
                a[2] = (short)f2b(clip100(f0.z));
                a[3] = (short)f2b(clip100(f0.w));
                a[4] = (short)f2b(clip100(f1.x));
                a[5] = (short)f2b(clip100(f1.y));
                a[6] = (short)f2b(clip100(f1.z));
                a[7] = (short)f2b(clip100(f1.w));
            }
#pragma unroll
            for (int nt = 0; nt < 8; ++nt) {
                const short8 b = *(const short8*)(wl + (nt * 16 + l16) * 136 + kc * 32 + kq);
                acc[nt] = __builtin_amdgcn_mfma_f32_16x16x32_bf16(a, b, acc[nt], 0, 0, 0);
            }
        }
    }

    const int r0 = blockIdx.x * 64 + wv * 16 + qd * 4;
#pragma unroll
    for (int nt = 0; nt < 8; ++nt) {
        const int col = nt * 16 + l16;
        const float bgv = bg[col];
#pragma unroll
        for (int r = 0; r < 4; ++r) {
            const int row = r0 + r;
            if (row < NN) {
                const float g = 1.f / (1.f + __expf(-(acc[nt][r] + bgv)));
                const unsigned int hu = ht[(wv * 16 + qd * 4 + r) * 68 + (col >> 1)];
                const float hv = (col & 1) ? bhi(hu) : blo(hu);
                __builtin_nontemporal_store(hv * g, &out[(long)row * 128 + col]);
            }
        }
    }
}

// ---------------- launch ----------------
extern "C" void kernel_launch(void* const* d_in, const int* in_sizes, int n_in,
                              void* d_out, int out_size, void* d_ws, size_t ws_size,
                              hipStream_t stream) {
    const float* x  = (const float*)d_in[0];
    const int*  eix = (const int*)d_in[1];
    const float* W1 = (const float*)d_in[2];
    const float* b1 = (const float*)d_in[3];
    const float* W2 = (const float*)d_in[4];
    const float* b2 = (const float*)d_in[5];
    const float* Wg = (const float*)d_in[6];
    const float* bg = (const float*)d_in[7];
    float* out = (float*)d_out;

    char* ws = (char*)d_ws;
    unsigned short* As   = (unsigned short*)ws;                     // 12,812,288 B
    unsigned short* hb   = (unsigned short*)(ws + 12812288);        // 12,812,288 B
    unsigned short* Wt1  = (unsigned short*)(ws + 25624576);        // 32,768 B
    unsigned short* Wt2  = (unsigned short*)(ws + 25657344);        // 32,768 B
    unsigned short* Wgt  = (unsigned short*)(ws + 25690112);        // 65,536 B
    int*   rowptr = (int*)(ws + 25755648);                          // 200,704 B
    float* dinv   = (float*)(ws + 25956352);                        // 200,704 B
    int*   gcur   = (int*)(ws + 26157056);                          // 1,024 B
    int*   esrc   = (int*)(ws + 26159104);                          // 3,200,000 B
    int2*  epair  = (int2*)(ws + 29359104);                         // 8,388,608 B
    // end ~37.7 MB

    const int ggrid = MPAD / 64;  // 782
    dim3 blk(256);

    hipMemsetAsync(gcur, 0, NB2 * sizeof(int), stream);

    // K1: CSR pass-A buckets (200 blocks) || weight convert (256 blocks)
    k_front<<<NCHB + 256, blk, 0, stream>>>(eix, epair, gcur, W1, W2, Wg, Wt1, Wt2, Wgt);

    // K2: CSR sort+rowptr+dinv (256 blocks) || layer-1 GEMM, unscaled (782)
    k_mid<<<NB2 + ggrid, blk, 0, stream>>>(epair, gcur, rowptr, dinv, esrc, x, Wt1, As);

    // K3: layer-1 aggregate + layer-2 GEMM fused -> hb (scaled layer-2 messages)
    k_ag1<<<ggrid, blk, 0, stream>>>((const unsigned int*)As, Wt2, hb,
                                     rowptr, esrc, dinv, b1);

    // K4: layer-2 aggregate + gate GEMM fused -> out
    k_ag2<<<ggrid, blk, 0, stream>>>((const unsigned int*)hb, x, Wgt,
                                     rowptr, esrc, dinv, b2, bg, out);
}

// Round 8
// 211.983 us; speedup vs baseline: 1.3773x; 1.3773x over previous
//
#include <hip/hip_runtime.h>
#include <hip/hip_bf16.h>

using short8 = __attribute__((ext_vector_type(8))) short;
using f32x4  = __attribute__((ext_vector_type(4))) float;

static constexpr int NN = 50000;   // nodes
static constexpr int NE = 800000;  // edges
static constexpr int MPAD = 50048; // 782 * 64 padded rows for bf16 activations
static constexpr int NB2 = 256;    // dst buckets
static constexpr int BNODE = 196;  // nodes per bucket (256*196 = 50176 >= NN)
static constexpr int CAPB = 4096;  // bucket capacity (mean 3125, sigma ~56)
static constexpr int NCHB = 200;   // pass-A chunks
static constexpr int CHB = NE / NCHB;  // 4000 edges per chunk (exact)

__device__ __forceinline__ float clip100(float v) { return fminf(fmaxf(v, -100.f), 100.f); }
__device__ __forceinline__ unsigned short f2b(float v) {
    __hip_bfloat16 h = __float2bfloat16(v);
    return *reinterpret_cast<unsigned short*>(&h);
}
__device__ __forceinline__ float blo(unsigned int u) { return __uint_as_float(u << 16); }
__device__ __forceinline__ float bhi(unsigned int u) { return __uint_as_float(u & 0xFFFF0000u); }
__device__ __forceinline__ float b2f(unsigned short u) {
    return __uint_as_float(((unsigned int)u) << 16);
}

// ---------------- K1: bucket (blocks 0..199) || weight cvt (blocks 200..455) -
__global__ __launch_bounds__(256) void k_front(const int* __restrict__ idx,
                                               int2* __restrict__ epair,
                                               int* __restrict__ gcur,
                                               const float* __restrict__ W1,
                                               const float* __restrict__ W2,
                                               const float* __restrict__ Wg,
                                               unsigned short* __restrict__ Wt1,
                                               unsigned short* __restrict__ Wt2,
                                               unsigned short* __restrict__ Wgt) {
    __shared__ int ls[CHB], ld[CHB];
    __shared__ int bcnt[NB2], bb[NB2], bofs[NB2];
    const int tid = threadIdx.x;
    if (blockIdx.x < NCHB) {
        const int beg = blockIdx.x * CHB;
        for (int i = tid; i < CHB; i += 256) {
            ls[i] = idx[beg + i];
            ld[i] = idx[NE + beg + i];
        }
        bcnt[tid] = 0;
        __syncthreads();
        for (int i = tid; i < CHB; i += 256) atomicAdd(&bcnt[ld[i] / BNODE], 1);
        __syncthreads();
        bb[tid] = atomicAdd(&gcur[tid], bcnt[tid]);
        bofs[tid] = 0;
        __syncthreads();
        for (int i = tid; i < CHB; i += 256) {
            const int d = ld[i];
            const int p = d / BNODE;
            const int pos = atomicAdd(&bofs[p], 1);
            epair[p * CAPB + bb[p] + pos] = make_int2(ls[i], d);
        }
    } else {
        const int i = (blockIdx.x - NCHB) * 256 + tid;  // 0..65535
        if (i < 16384) {
            const int n = i >> 7, k = i & 127;
            Wt1[i] = f2b(W1[k * 128 + n]);
        } else if (i < 32768) {
            const int j = i - 16384;
            const int n = j >> 7, k = j & 127;
            Wt2[j] = f2b(W2[k * 128 + n]);
        } else {
            const int j = i - 32768;
            const int n = j >> 8, k = j & 255;
            Wgt[j] = f2b(Wg[k * 128 + n]);
        }
    }
}

// ---------------- K2: sortfill (blocks 0..255) || layer-1 GEMM (256..1037) ---
// sortfill scatters esrc DIRECTLY (no srt LDS stage): union drops 52.2->35.8 KB
// so the GEMM blocks get 4 blocks/CU instead of 3. Scatter window is 12.5 KB
// per bucket -> L2-absorbed.
__global__ __launch_bounds__(256) void k_mid(const int2* __restrict__ epair,
                                             const int* __restrict__ gcur,
                                             int* __restrict__ rowptr,
                                             float* __restrict__ dinv,
                                             int* __restrict__ esrc,
                                             const float* __restrict__ x,
                                             const unsigned short* __restrict__ Wt,
                                             unsigned short* __restrict__ Cb) {
    __shared__ alignas(16) char smem[CAPB * 2 * 4 + 3 * 256 * 4];  // 35840 B union
    const int tid = threadIdx.x;
    if (blockIdx.x < NB2) {
        int* ls   = (int*)smem;
        int* ld   = ls + CAPB;
        int* cntL = ld + CAPB;
        int* sc   = cntL + 256;
        int* cur  = sc + 256;
        const int t = tid;
        const int b = blockIdx.x;
        sc[t] = gcur[t];
        __syncthreads();
        for (int off = 1; off < 256; off <<= 1) {
            const int add = (t >= off) ? sc[t - off] : 0;
            __syncthreads();
            sc[t] += add;
            __syncthreads();
        }
        const int ne = gcur[b];
        const int base = sc[b] - ne;  // exclusive prefix for bucket b
        const int nb0 = b * BNODE;
        const int nn = min(NN - nb0, BNODE);
        if (b == 0 && t == 0) rowptr[NN] = NE;

        for (int i = t; i < ne; i += 256) {
            const int2 p = epair[b * CAPB + i];
            ls[i] = p.x;
            ld[i] = p.y - nb0;  // node-local index in [0, nn)
        }
        cntL[t] = 0;
        __syncthreads();
        for (int i = t; i < ne; i += 256) atomicAdd(&cntL[ld[i]], 1);
        __syncthreads();
        sc[t] = cntL[t];
        __syncthreads();
        for (int off = 1; off < 256; off <<= 1) {
            const int add = (t >= off) ? sc[t - off] : 0;
            __syncthreads();
            sc[t] += add;
            __syncthreads();
        }
        const int excl = sc[t] - cntL[t];
        cur[t] = excl;
        if (t < nn) {
            rowptr[nb0 + t] = base + excl;
            dinv[nb0 + t] = rsqrtf(1.f + (float)cntL[t]);
        }
        __syncthreads();
        for (int i = t; i < ne; i += 256) {
            const int pos = base + atomicAdd(&cur[ld[i]], 1);
            esrc[pos] = ls[i];   // direct scatter, 12.5 KB window (L2)
        }
    } else {
        unsigned short* wl = (unsigned short*)smem;  // 128 x 136 = 34816 B
#pragma unroll
        for (int j = tid; j < 2048; j += 256) {  // 2048 = 128 rows x 16 short8
            const int row = j >> 4, c8 = j & 15;
            *(short8*)(wl + row * 136 + c8 * 8) = *(const short8*)(Wt + row * 128 + c8 * 8);
        }
        __syncthreads();

        const int wv = tid >> 6;
        const int ln = tid & 63;
        const int l16 = ln & 15;
        const int qd = ln >> 4;
        const int rowb = (blockIdx.x - NB2) * 64 + wv * 16;
        const long arow = rowb + l16;
        const int kq = qd * 8;

        f32x4 acc[8];
#pragma unroll
        for (int i = 0; i < 8; ++i) acc[i] = (f32x4){0.f, 0.f, 0.f, 0.f};

#pragma unroll
        for (int kc = 0; kc < 4; ++kc) {
            short8 a = (short8){0, 0, 0, 0, 0, 0, 0, 0};
            if (arow < NN) {
                const float* fp = x + arow * 128 + kc * 32 + kq;
                const float4 f0 = *(const float4*)fp;
                const float4 f1 = *(const float4*)(fp + 4);
                a[0] = (short)f2b(clip100(f0.x));
                a[1] = (short)f2b(clip100(f0.y));
                a[2] = (short)f2b(clip100(f0.z));
                a[3] = (short)f2b(clip100(f0.w));
                a[4] = (short)f2b(clip100(f1.x));
                a[5] = (short)f2b(clip100(f1.y));
                a[6] = (short)f2b(clip100(f1.z));
                a[7] = (short)f2b(clip100(f1.w));
            }
#pragma unroll
            for (int nt = 0; nt < 8; ++nt) {
                const short8 b = *(const short8*)(wl + (nt * 16 + l16) * 136 + kc * 32 + kq);
                acc[nt] = __builtin_amdgcn_mfma_f32_16x16x32_bf16(a, b, acc[nt], 0, 0, 0);
            }
        }

        const int r0 = rowb + qd * 4;
#pragma unroll
        for (int r = 0; r < 4; ++r) {
            const int row = r0 + r;
            if (row < NN) {
#pragma unroll
                for (int nt = 0; nt < 8; ++nt) {
                    Cb[(long)row * 128 + nt * 16 + l16] = f2b(acc[nt][r]);
                }
            }
        }
    }
}

// ---------------- layer-2 MFMA GEMM (K=128, LDS-staged Wt, dinv-scaled) ------
__global__ __launch_bounds__(256) void k_mfma2(const unsigned short* __restrict__ Ab,
                                               const unsigned short* __restrict__ Wt,
                                               unsigned short* __restrict__ Cb,
                                               const float* __restrict__ dinv) {
    __shared__ unsigned short wl[128 * 136];
    const int tid = threadIdx.x;
#pragma unroll
    for (int j = tid; j < 2048; j += 256) {
        const int row = j >> 4, c8 = j & 15;
        *(short8*)(wl + row * 136 + c8 * 8) = *(const short8*)(Wt + row * 128 + c8 * 8);
    }
    __syncthreads();

    const int wv = tid >> 6;
    const int ln = tid & 63;
    const int l16 = ln & 15;
    const int qd = ln >> 4;
    const int rowb = blockIdx.x * 64 + wv * 16;
    const long arow = rowb + l16;
    const int kq = qd * 8;

    f32x4 acc[8];
#pragma unroll
    for (int i = 0; i < 8; ++i) acc[i] = (f32x4){0.f, 0.f, 0.f, 0.f};

#pragma unroll
    for (int kc = 0; kc < 4; ++kc) {
        const short8 a = *(const short8*)(Ab + arow * 128 + kc * 32 + kq);
#pragma unroll
        for (int nt = 0; nt < 8; ++nt) {
            const short8 b = *(const short8*)(wl + (nt * 16 + l16) * 136 + kc * 32 + kq);
            acc[nt] = __builtin_amdgcn_mfma_f32_16x16x32_bf16(a, b, acc[nt], 0, 0, 0);
        }
    }

    const int r0 = rowb + qd * 4;
#pragma unroll
    for (int r = 0; r < 4; ++r) {
        const int row = r0 + r;
        if (row < NN) {
            const float dv = dinv[row];
#pragma unroll
            for (int nt = 0; nt < 8; ++nt) {
                Cb[(long)row * 128 + nt * 16 + l16] = f2b(acc[nt][r] * dv);
            }
        }
    }
}

// ---------------- gate MFMA (K=256, split-K LDS staging: 34.8 KB not 67.6) ---
__global__ __launch_bounds__(256) void k_mfma_gate(const unsigned short* __restrict__ Ab,
                                                   const float* __restrict__ Af,
                                                   const unsigned short* __restrict__ Wt,
                                                   const float* __restrict__ bg,
                                                   float* __restrict__ out) {
    __shared__ unsigned short wl[128 * 136];   // one 128x128 K-half at a time
    const int tid = threadIdx.x;
    const int wv = tid >> 6;
    const int ln = tid & 63;
    const int l16 = ln & 15;
    const int qd = ln >> 4;
    const int rowb = blockIdx.x * 64 + wv * 16;
    const long arow = rowb + l16;
    const int kq = qd * 8;

    f32x4 acc[8];
#pragma unroll
    for (int i = 0; i < 8; ++i) acc[i] = (f32x4){0.f, 0.f, 0.f, 0.f};

    // phase 1: K = 0..127 (h part, bf16 A)
#pragma unroll
    for (int j = tid; j < 2048; j += 256) {
        const int row = j >> 4, c8 = j & 15;
        *(short8*)(wl + row * 136 + c8 * 8) = *(const short8*)(Wt + row * 256 + c8 * 8);
    }
    __syncthreads();
    {
        const unsigned short* ap = Ab + arow * 128 + kq;
#pragma unroll
        for (int kc = 0; kc < 4; ++kc) {
            const short8 a = *(const short8*)(ap + kc * 32);
#pragma unroll
            for (int nt = 0; nt < 8; ++nt) {
                const short8 b = *(const short8*)(wl + (nt * 16 + l16) * 136 + kc * 32 + kq);
                acc[nt] = __builtin_amdgcn_mfma_f32_16x16x32_bf16(a, b, acc[nt], 0, 0, 0);
            }
        }
    }
    __syncthreads();  // all phase-1 reads of wl complete before overwrite

    // phase 2: K = 128..255 (x part, converted f32 A)
#pragma unroll
    for (int j = tid; j < 2048; j += 256) {
        const int row = j >> 4, c8 = j & 15;
        *(short8*)(wl + row * 136 + c8 * 8) = *(const short8*)(Wt + row * 256 + 128 + c8 * 8);
    }
    __syncthreads();
    {
        const bool valid = arow < NN;
        const float* fp = Af + arow * 128 + kq;
#pragma unroll
        for (int kc = 0; kc < 4; ++kc) {
            short8 a = (short8){0, 0, 0, 0, 0, 0, 0, 0};
            if (valid) {
                const float4 f0 = *(const float4*)(fp + kc * 32);
                const float4 f1 = *(const float4*)(fp + kc * 32 + 4);
                a[0] = (short)f2b(clip100(f0.x));
                a[1] = (short)f2b(clip100(f0.y));
                a[2] = (short)f2b(clip100(f0.z));
                a[3] = (short)f2b(clip100(f0.w));
                a[4] = (short)f2b(clip100(f1.x));
                a[5] = (short)f2b(clip100(f1.y));
                a[6] = (short)f2b(clip100(f1.z));
                a[7] = (short)f2b(clip100(f1.w));
            }
#pragma unroll
            for (int nt = 0; nt < 8; ++nt) {
                const short8 b = *(const short8*)(wl + (nt * 16 + l16) * 136 + kc * 32 + kq);
                acc[nt] = __builtin_amdgcn_mfma_f32_16x16x32_bf16(a, b, acc[nt], 0, 0, 0);
            }
        }
    }

    const int r0 = rowb + qd * 4;
#pragma unroll
    for (int nt = 0; nt < 8; ++nt) {
        const int col = nt * 16 + l16;
        const float bgv = bg[col];
#pragma unroll
        for (int r = 0; r < 4; ++r) {
            const int row = r0 + r;
            if (row < NN) {
                const float g = 1.f / (1.f + __expf(-(acc[nt][r] + bgv)));
                const float ov = b2f(Ab[(long)row * 128 + col]) * g;
                __builtin_nontemporal_store(ov, &out[(long)row * 128 + col]);
            }
        }
    }
}

// ---------------- fused aggregation (bf16 messages, 16x unroll) --------------
// d wave-uniform via readfirstlane: rowptr/esrc/dinv loads are scalar, gather
// base is SGPR + lane*4. 16 gathers in flight in the main loop.
// One wave per node (50k waves) — max TLP; R5/R7 proved fewer, longer-running
// waves lose badly on this latency-bound gather.
template <bool RES, bool ESCALE>
__global__ __launch_bounds__(256) void k_aggr(const unsigned int* __restrict__ As2,
                                              unsigned short* __restrict__ Bb,
                                              const int* __restrict__ rowptr,
                                              const int* __restrict__ esrc,
                                              const float* __restrict__ dinv,
                                              const float* __restrict__ bias,
                                              const float* __restrict__ x) {
    const int d = __builtin_amdgcn_readfirstlane((blockIdx.x * 256 + threadIdx.x) >> 6);
    if (d >= NN) return;
    const int lane = threadIdx.x & 63;
    const float dd = dinv[d];

    const unsigned int u = As2[(long)d * 64 + lane];  // self term
    float2 acc;
    if (ESCALE) {
        acc.x = blo(u) * dd;
        acc.y = bhi(u) * dd;
    } else {
        acc.x = blo(u);
        acc.y = bhi(u);
    }

    const int beg = rowptr[d];
    const int end = rowptr[d + 1];
    int i = beg;
    for (; i + 16 <= end; i += 16) {
        int s[16];
#pragma unroll
        for (int e = 0; e < 16; ++e) s[e] = esrc[i + e];
        unsigned int v[16];
#pragma unroll
        for (int e = 0; e < 16; ++e) v[e] = As2[(long)s[e] * 64 + lane];
        if (ESCALE) {
            float px = 0.f, py = 0.f;
#pragma unroll
            for (int e = 0; e < 16; ++e) {
                const float w = dinv[s[e]];
                px = fmaf(blo(v[e]), w, px);
                py = fmaf(bhi(v[e]), w, py);
            }
            acc.x += px;
            acc.y += py;
        } else {
            float px = 0.f, py = 0.f;
#pragma unroll
            for (int e = 0; e < 16; ++e) {
                px += blo(v[e]);
                py += bhi(v[e]);
            }
            acc.x += px;
            acc.y += py;
        }
    }
    if (i + 8 <= end) {
        const int s0 = esrc[i + 0], s1 = esrc[i + 1], s2 = esrc[i + 2], s3 = esrc[i + 3];
        const int s4 = esrc[i + 4], s5 = esrc[i + 5], s6 = esrc[i + 6], s7 = esrc[i + 7];
        const unsigned int v0 = As2[(long)s0 * 64 + lane];
        const unsigned int v1 = As2[(long)s1 * 64 + lane];
        const unsigned int v2 = As2[(long)s2 * 64 + lane];
        const unsigned int v3 = As2[(long)s3 * 64 + lane];
        const unsigned int v4 = As2[(long)s4 * 64 + lane];
        const unsigned int v5 = As2[(long)s5 * 64 + lane];
        const unsigned int v6 = As2[(long)s6 * 64 + lane];
        const unsigned int v7 = As2[(long)s7 * 64 + lane];
        if (ESCALE) {
            const float w0 = dinv[s0], w1 = dinv[s1], w2 = dinv[s2], w3 = dinv[s3];
            const float w4 = dinv[s4], w5 = dinv[s5], w6 = dinv[s6], w7 = dinv[s7];
            acc.x += ((blo(v0) * w0 + blo(v1) * w1) + (blo(v2) * w2 + blo(v3) * w3)) +
                     ((blo(v4) * w4 + blo(v5) * w5) + (blo(v6) * w6 + blo(v7) * w7));
            acc.y += ((bhi(v0) * w0 + bhi(v1) * w1) + (bhi(v2) * w2 + bhi(v3) * w3)) +
                     ((bhi(v4) * w4 + bhi(v5) * w5) + (bhi(v6) * w6 + bhi(v7) * w7));
        } else {
            acc.x += ((blo(v0) + blo(v1)) + (blo(v2) + blo(v3))) +
                     ((blo(v4) + blo(v5)) + (blo(v6) + blo(v7)));
            acc.y += ((bhi(v0) + bhi(v1)) + (bhi(v2) + bhi(v3))) +
                     ((bhi(v4) + bhi(v5)) + (bhi(v6) + bhi(v7)));
        }
        i += 8;
    }
    if (i + 4 <= end) {
        const int s0 = esrc[i + 0], s1 = esrc[i + 1], s2 = esrc[i + 2], s3 = esrc[i + 3];
        const unsigned int v0 = As2[(long)s0 * 64 + lane];
        const unsigned int v1 = As2[(long)s1 * 64 + lane];
        const unsigned int v2 = As2[(long)s2 * 64 + lane];
        const unsigned int v3 = As2[(long)s3 * 64 + lane];
        if (ESCALE) {
            const float w0 = dinv[s0], w1 = dinv[s1], w2 = dinv[s2], w3 = dinv[s3];
            acc.x += (blo(v0) * w0 + blo(v1) * w1) + (blo(v2) * w2 + blo(v3) * w3);
            acc.y += (bhi(v0) * w0 + bhi(v1) * w1) + (bhi(v2) * w2 + bhi(v3) * w3);
        } else {
            acc.x += (blo(v0) + blo(v1)) + (blo(v2) + blo(v3));
            acc.y += (bhi(v0) + bhi(v1)) + (bhi(v2) + bhi(v3));
        }
        i += 4;
    }
    for (; i < end; ++i) {
        const int s = esrc[i];
        const unsigned int v = As2[(long)s * 64 + lane];
        if (ESCALE) {
            const float w = dinv[s];
            acc.x = fmaf(blo(v), w, acc.x);
            acc.y = fmaf(bhi(v), w, acc.y);
        } else {
            acc.x += blo(v);
            acc.y += bhi(v);
        }
    }

    const float2 bv = ((const float2*)bias)[lane];
    acc.x = fmaxf(fmaf(acc.x, dd, bv.x), 0.f);
    acc.y = fmaxf(fmaf(acc.y, dd, bv.y), 0.f);
    if (RES) {
        const float2 xv = ((const float2*)x)[(long)d * 64 + lane];
        acc.x += clip100(xv.x);
        acc.y += clip100(xv.y);
    }
    const unsigned int pack = (unsigned int)f2b(acc.x) | ((unsigned int)f2b(acc.y) << 16);
    ((unsigned int*)Bb)[(long)d * 64 + lane] = pack;
}

// ---------------- launch ----------------
extern "C" void kernel_launch(void* const* d_in, const int* in_sizes, int n_in,
                              void* d_out, int out_size, void* d_ws, size_t ws_size,
                              hipStream_t stream) {
    const float* x  = (const float*)d_in[0];
    const int*  eix = (const int*)d_in[1];
    const float* W1 = (const float*)d_in[2];
    const float* b1 = (const float*)d_in[3];
    const float* W2 = (const float*)d_in[4];
    const float* b2 = (const float*)d_in[5];
    const float* Wg = (const float*)d_in[6];
    const float* bg = (const float*)d_in[7];
    float* out = (float*)d_out;

    char* ws = (char*)d_ws;
    unsigned short* As   = (unsigned short*)ws;                     // 12,812,288 B
    unsigned short* hb   = (unsigned short*)(ws + 12812288);        // 12,812,288 B
    unsigned short* Wt1  = (unsigned short*)(ws + 25624576);        // 32,768 B
    unsigned short* Wt2  = (unsigned short*)(ws + 25657344);        // 32,768 B
    unsigned short* Wgt  = (unsigned short*)(ws + 25690112);        // 65,536 B
    int*   rowptr = (int*)(ws + 25755648);                          // 200,704 B
    float* dinv   = (float*)(ws + 25956352);                        // 200,704 B
    int*   gcur   = (int*)(ws + 26157056);                          // 1,024 B
    int*   esrc   = (int*)(ws + 26159104);                          // 3,200,000 B
    int2*  epair  = (int2*)(ws + 29359104);                         // 8,388,608 B
    // end ~37.7 MB

    const int ggrid = MPAD / 64;  // 782
    dim3 blk(256);

    hipMemsetAsync(gcur, 0, NB2 * sizeof(int), stream);

    // K1: CSR pass-A buckets (200 blocks) || weight convert (256 blocks)
    k_front<<<NCHB + 256, blk, 0, stream>>>(eix, epair, gcur, W1, W2, Wg, Wt1, Wt2, Wgt);

    // K2: CSR sort+rowptr+dinv (256 blocks) || layer-1 GEMM, unscaled (782)
    k_mid<<<NB2 + ggrid, blk, 0, stream>>>(epair, gcur, rowptr, dinv, esrc, x, Wt1, As);

    // layer 1 aggregate: h1 = bf16(relu(dinv_d * (Σ As[s]*dinv_s + As[d]*dinv_d) + b1))
    k_aggr<false, true><<<(NN * 64 + 255) / 256, blk, 0, stream>>>(
        (const unsigned int*)As, hb, rowptr, esrc, dinv, b1, nullptr);

    // layer 2 GEMM: As = bf16((h1 @ W2) * dinv_row)
    k_mfma2<<<ggrid, blk, 0, stream>>>(hb, Wt2, As, dinv);

    // layer 2 aggregate: hb = bf16(relu(dinv_d * ΣAs + b2) + clip(x))
    k_aggr<true, false><<<(NN * 64 + 255) / 256, blk, 0, stream>>>(
        (const unsigned int*)As, hb, rowptr, esrc, dinv, b2, x);

    // gate: G = [hb | clip(x)] @ Wgt (K=256) ; out = b2f(hb) * sigmoid(G + bg)
    k_mfma_gate<<<ggrid, blk, 0, stream>>>(hb, x, Wgt, bg, out);
}